// Round 1
// baseline (643.175 us; speedup 1.0000x reference)
//
#include <hip/hip_runtime.h>
#include <cstdint>
#include <cstddef>

// ---------------- CSR build ----------------

__global__ __launch_bounds__(256) void k_count(const int* __restrict__ dst,
                                               int* __restrict__ cnt, int E) {
    int e = blockIdx.x * 256 + threadIdx.x;
    if (e < E) atomicAdd(&cnt[dst[e]], 1);
}

__global__ __launch_bounds__(256) void k_dinv(const int* __restrict__ cnt,
                                              float* __restrict__ dinv, int n) {
    int i = blockIdx.x * 256 + threadIdx.x;
    if (i < n) dinv[i] = rsqrtf((float)cnt[i] + 1.0f);  // +1 self-loop, always > 0
}

__global__ __launch_bounds__(256) void k_block_reduce(const int* __restrict__ cnt,
                                                      int* __restrict__ bsum, int n) {
    __shared__ int sd[256];
    int i = blockIdx.x * 256 + threadIdx.x;
    sd[threadIdx.x] = (i < n) ? cnt[i] : 0;
    __syncthreads();
    for (int s = 128; s > 0; s >>= 1) {
        if (threadIdx.x < s) sd[threadIdx.x] += sd[threadIdx.x + s];
        __syncthreads();
    }
    if (threadIdx.x == 0) bsum[blockIdx.x] = sd[0];
}

// single block, nb <= 256: in-place exclusive scan of bsum
__global__ __launch_bounds__(256) void k_scan_bsum(int* __restrict__ bsum, int nb) {
    __shared__ int sd[256];
    int t = threadIdx.x;
    int v = (t < nb) ? bsum[t] : 0;
    sd[t] = v;
    __syncthreads();
    for (int off = 1; off < 256; off <<= 1) {
        int add = (t >= off) ? sd[t - off] : 0;
        __syncthreads();
        sd[t] += add;
        __syncthreads();
    }
    if (t < nb) bsum[t] = sd[t] - v;  // exclusive
}

__global__ __launch_bounds__(256) void k_scan_write(const int* __restrict__ cnt,
                                                    const int* __restrict__ bsum,
                                                    int* __restrict__ rowptr,
                                                    int* __restrict__ cursor, int n) {
    __shared__ int sd[256];
    int t = threadIdx.x;
    int i = blockIdx.x * 256 + t;
    int v = (i < n) ? cnt[i] : 0;
    sd[t] = v;
    __syncthreads();
    for (int off = 1; off < 256; off <<= 1) {
        int add = (t >= off) ? sd[t - off] : 0;
        __syncthreads();
        sd[t] += add;
        __syncthreads();
    }
    int excl = sd[t] - v + bsum[blockIdx.x];
    if (i < n) { rowptr[i] = excl; cursor[i] = excl; }
}

__global__ __launch_bounds__(256) void k_scatter(const int* __restrict__ src,
                                                 const int* __restrict__ dst,
                                                 int* __restrict__ cursor,
                                                 int* __restrict__ esrc, int E) {
    int e = blockIdx.x * 256 + threadIdx.x;
    if (e < E) {
        int d = dst[e];
        int pos = atomicAdd(&cursor[d], 1);
        esrc[pos] = src[e];
    }
}

// ---------------- GEMM: C[n x 128] = A[n x 128] @ W[128 x 128] ----------------
// block = 128 threads (thread = output col), 16 rows per block.
// W staged in LDS (64 KB); A-row reads are block-uniform -> s_load_dwordx4.

__global__ __launch_bounds__(128) void k_gemm128(const float* __restrict__ A,
                                                 const float* __restrict__ Wg,
                                                 float* __restrict__ C, int nrows) {
    __shared__ float Ws[128 * 128];
    const int c = threadIdx.x;
    {
        const float4* Wg4 = reinterpret_cast<const float4*>(Wg);
        float4* Ws4 = reinterpret_cast<float4*>(Ws);
        for (int i = c; i < 128 * 128 / 4; i += 128) Ws4[i] = Wg4[i];
    }
    __syncthreads();

    const int r0 = blockIdx.x * 16;
    float acc[16];
#pragma unroll
    for (int j = 0; j < 16; j++) acc[j] = 0.0f;

    const float4* A4 = reinterpret_cast<const float4*>(A);
    for (int kk = 0; kk < 32; kk++) {
        float w0 = Ws[(kk * 4 + 0) * 128 + c];
        float w1 = Ws[(kk * 4 + 1) * 128 + c];
        float w2 = Ws[(kk * 4 + 2) * 128 + c];
        float w3 = Ws[(kk * 4 + 3) * 128 + c];
#pragma unroll
        for (int j = 0; j < 16; j++) {
            float4 av = A4[(size_t)(r0 + j) * 32 + kk];  // uniform -> scalar load
            acc[j] = fmaf(av.x, w0, acc[j]);
            acc[j] = fmaf(av.y, w1, acc[j]);
            acc[j] = fmaf(av.z, w2, acc[j]);
            acc[j] = fmaf(av.w, w3, acc[j]);
        }
    }
#pragma unroll
    for (int j = 0; j < 16; j++) {
        int r = r0 + j;
        if (r < nrows) C[(size_t)r * 128 + c] = acc[j];
    }
}

// ---------------- Gather (pull-style message passing) ----------------
// one wave per dst node; lane owns 2 consecutive cols (float2 = 512 B/row/wave)

__global__ __launch_bounds__(256) void k_gather(const float* __restrict__ hw,
                                                const float* __restrict__ dinv,
                                                const int* __restrict__ rowptr,
                                                const int* __restrict__ cnt,
                                                const int* __restrict__ esrc,
                                                const float* __restrict__ bias,
                                                float* __restrict__ outp, int n) {
    int wave = threadIdx.x >> 6;
    int lane = threadIdx.x & 63;
    int node = blockIdx.x * 4 + wave;
    if (node >= n) return;

    float di = dinv[node];
    int start = rowptr[node];
    int deg = cnt[node];

    const float2* hn = reinterpret_cast<const float2*>(hw + (size_t)node * 128);
    float2 v = hn[lane];
    float sw = di * di;                 // self-loop weight
    float acc0 = v.x * sw;
    float acc1 = v.y * sw;

    for (int j = 0; j < deg; j++) {
        int s = esrc[start + j];
        float w = dinv[s] * di;
        const float2* hs = reinterpret_cast<const float2*>(hw + (size_t)s * 128);
        float2 u = hs[lane];
        acc0 = fmaf(u.x, w, acc0);
        acc1 = fmaf(u.y, w, acc1);
    }

    const float2* b2 = reinterpret_cast<const float2*>(bias);
    float2 bb = b2[lane];
    acc0 += bb.x;
    acc1 += bb.y;
    float2 o;
    o.x = acc0 > 0.0f ? acc0 : 0.0f;
    o.y = acc1 > 0.0f ? acc1 : 0.0f;
    reinterpret_cast<float2*>(outp + (size_t)node * 128)[lane] = o;
}

// ---------------- Max pool (post-ReLU, values >= 0) ----------------

__global__ __launch_bounds__(256) void k_pool(const float* __restrict__ h,
                                              int* __restrict__ pooledBits, int n) {
    int c = threadIdx.x & 127;
    int half = threadIdx.x >> 7;
    float m = 0.0f;
    for (int r = blockIdx.x * 2 + half; r < n; r += gridDim.x * 2)
        m = fmaxf(m, h[(size_t)r * 128 + c]);
    atomicMax(&pooledBits[c], __float_as_int(m));  // valid: m >= 0
}

__global__ __launch_bounds__(64) void k_fc(const int* __restrict__ pooledBits,
                                           const float* __restrict__ Wfc,
                                           const float* __restrict__ bfc,
                                           float* __restrict__ out) {
    int c = threadIdx.x;  // 0..63
    float acc = bfc[c];
    for (int k = 0; k < 128; k++)
        acc = fmaf(__int_as_float(pooledBits[k]), Wfc[k * 64 + c], acc);
    out[c] = acc;
}

// ---------------- launch ----------------

extern "C" void kernel_launch(void* const* d_in, const int* in_sizes, int n_in,
                              void* d_out, int out_size, void* d_ws, size_t ws_size,
                              hipStream_t stream) {
    const float* x   = (const float*)d_in[0];
    const int* edges = (const int*)d_in[1];
    const float* W1  = (const float*)d_in[2];
    const float* b1  = (const float*)d_in[3];
    const float* W2  = (const float*)d_in[4];
    const float* b2  = (const float*)d_in[5];
    const float* Wfc = (const float*)d_in[6];
    const float* bfc = (const float*)d_in[7];
    float* out = (float*)d_out;

    const int N = in_sizes[0] / 128;
    const int E = in_sizes[1] / 2;
    const int* esrc_in = edges;       // edge_index[0]
    const int* edst_in = edges + E;   // edge_index[1]

    // workspace layout (256B aligned chunks)
    auto align256 = [](size_t v) { return (v + 255) & ~(size_t)255; };
    char* p = (char*)d_ws;
    size_t off = 0;
    int* cnt      = (int*)(p + off); off = align256(off + (size_t)N * 4);
    int* rowptr   = (int*)(p + off); off = align256(off + (size_t)N * 4);
    int* cursor   = (int*)(p + off); off = align256(off + (size_t)N * 4);
    float* dinv   = (float*)(p + off); off = align256(off + (size_t)N * 4);
    int* bsum     = (int*)(p + off); off = align256(off + 256 * 4);
    int* pooled   = (int*)(p + off); off = align256(off + 128 * 4);
    int* esrc     = (int*)(p + off); off = align256(off + (size_t)E * 4);
    float* bufA   = (float*)(p + off); off = align256(off + (size_t)N * 128 * 4);
    float* bufB   = (float*)(p + off); off = align256(off + (size_t)N * 128 * 4);
    (void)ws_size; (void)n_in; (void)out_size;

    const int EB = (E + 255) / 256;       // 3125
    const int NB = (N + 255) / 256;       // 196 (<=256 for single-block scan)
    const int GB = (N + 15) / 16;         // gemm blocks
    const int HB = (N + 3) / 4;           // gather blocks

    hipMemsetAsync(cnt, 0, (size_t)N * 4, stream);
    hipMemsetAsync(pooled, 0, 128 * 4, stream);

    k_count<<<EB, 256, 0, stream>>>(edst_in, cnt, E);
    k_dinv<<<NB, 256, 0, stream>>>(cnt, dinv, N);
    k_block_reduce<<<NB, 256, 0, stream>>>(cnt, bsum, N);
    k_scan_bsum<<<1, 256, 0, stream>>>(bsum, NB);
    k_scan_write<<<NB, 256, 0, stream>>>(cnt, bsum, rowptr, cursor, N);
    k_scatter<<<EB, 256, 0, stream>>>(esrc_in, edst_in, cursor, esrc, E);

    // layer 1
    k_gemm128<<<GB, 128, 0, stream>>>(x, W1, bufA, N);
    k_gather<<<HB, 256, 0, stream>>>(bufA, dinv, rowptr, cnt, esrc, b1, bufB, N);
    // layer 2
    k_gemm128<<<GB, 128, 0, stream>>>(bufB, W2, bufA, N);
    k_gather<<<HB, 256, 0, stream>>>(bufA, dinv, rowptr, cnt, esrc, b2, bufB, N);

    // pool + fc
    k_pool<<<512, 256, 0, stream>>>(bufB, pooled, N);
    k_fc<<<1, 64, 0, stream>>>(pooled, Wfc, bfc, out);
}

// Round 2
// 401.073 us; speedup vs baseline: 1.6036x; 1.6036x over previous
//
#include <hip/hip_runtime.h>
#include <cstdint>
#include <cstddef>

// ---------------- CSR build ----------------

__global__ __launch_bounds__(256) void k_count(const int* __restrict__ dst,
                                               int* __restrict__ cnt, int E) {
    int e = blockIdx.x * 256 + threadIdx.x;
    if (e < E) atomicAdd(&cnt[dst[e]], 1);
}

__global__ __launch_bounds__(256) void k_dinv(const int* __restrict__ cnt,
                                              float* __restrict__ dinv, int n) {
    int i = blockIdx.x * 256 + threadIdx.x;
    if (i < n) dinv[i] = rsqrtf((float)cnt[i] + 1.0f);  // +1 self-loop, always > 0
}

__global__ __launch_bounds__(256) void k_block_reduce(const int* __restrict__ cnt,
                                                      int* __restrict__ bsum, int n) {
    __shared__ int sd[256];
    int i = blockIdx.x * 256 + threadIdx.x;
    sd[threadIdx.x] = (i < n) ? cnt[i] : 0;
    __syncthreads();
    for (int s = 128; s > 0; s >>= 1) {
        if (threadIdx.x < s) sd[threadIdx.x] += sd[threadIdx.x + s];
        __syncthreads();
    }
    if (threadIdx.x == 0) bsum[blockIdx.x] = sd[0];
}

// single block, nb <= 256: in-place exclusive scan of bsum
__global__ __launch_bounds__(256) void k_scan_bsum(int* __restrict__ bsum, int nb) {
    __shared__ int sd[256];
    int t = threadIdx.x;
    int v = (t < nb) ? bsum[t] : 0;
    sd[t] = v;
    __syncthreads();
    for (int off = 1; off < 256; off <<= 1) {
        int add = (t >= off) ? sd[t - off] : 0;
        __syncthreads();
        sd[t] += add;
        __syncthreads();
    }
    if (t < nb) bsum[t] = sd[t] - v;  // exclusive
}

__global__ __launch_bounds__(256) void k_scan_write(const int* __restrict__ cnt,
                                                    const int* __restrict__ bsum,
                                                    int* __restrict__ rowptr,
                                                    int* __restrict__ cursor, int n) {
    __shared__ int sd[256];
    int t = threadIdx.x;
    int i = blockIdx.x * 256 + t;
    int v = (i < n) ? cnt[i] : 0;
    sd[t] = v;
    __syncthreads();
    for (int off = 1; off < 256; off <<= 1) {
        int add = (t >= off) ? sd[t - off] : 0;
        __syncthreads();
        sd[t] += add;
        __syncthreads();
    }
    int excl = sd[t] - v + bsum[blockIdx.x];
    if (i < n) { rowptr[i] = excl; cursor[i] = excl; }
}

__global__ __launch_bounds__(256) void k_scatter(const int* __restrict__ src,
                                                 const int* __restrict__ dst,
                                                 int* __restrict__ cursor,
                                                 int* __restrict__ esrc, int E) {
    int e = blockIdx.x * 256 + threadIdx.x;
    if (e < E) {
        int d = dst[e];
        int pos = atomicAdd(&cursor[d], 1);
        esrc[pos] = src[e];
    }
}

// ---------------- GEMM: C[n x 128] = A[n x 128] @ W[128 x 128] ----------------
// 256 threads = 4 waves; tile 64 rows x 128 cols; thread = (tr,tc):
//   tr = tid>>5 -> 8 rows (r0 + tr*8 + j), tc = tid&31 -> 4 cols (tc*4..tc*4+3)
// W staged in LDS (64 KB, read as float4 rows, conflict-free);
// A read directly from global (2 distinct addrs per load instr -> L1 broadcast).
// acc[8][4] = 32 independent FMA chains.

__global__ __launch_bounds__(256, 2) void k_gemm128(const float* __restrict__ A,
                                                    const float* __restrict__ Wg,
                                                    float* __restrict__ C, int nrows) {
    __shared__ float Ws[128 * 128];
    const int tid = threadIdx.x;
    {
        const float4* Wg4 = reinterpret_cast<const float4*>(Wg);
        float4* Ws4 = reinterpret_cast<float4*>(Ws);
#pragma unroll
        for (int i = 0; i < 16; i++) Ws4[tid + 256 * i] = Wg4[tid + 256 * i];
    }
    __syncthreads();

    const int tc = tid & 31;
    const int tr = tid >> 5;
    const int r0 = blockIdx.x * 64 + tr * 8;

    // clamp row indices so tail-block loads stay in bounds (stores are guarded)
    size_t arow[8];
#pragma unroll
    for (int j = 0; j < 8; j++) {
        int r = r0 + j;
        if (r > nrows - 1) r = nrows - 1;
        arow[j] = (size_t)r * 32;
    }

    float acc[8][4];
#pragma unroll
    for (int j = 0; j < 8; j++)
#pragma unroll
        for (int c = 0; c < 4; c++) acc[j][c] = 0.0f;

    const float4* A4 = reinterpret_cast<const float4*>(A);

#pragma unroll 2
    for (int k4 = 0; k4 < 32; k4++) {
        const float4 w0 = *reinterpret_cast<const float4*>(&Ws[(k4 * 4 + 0) * 128 + tc * 4]);
        const float4 w1 = *reinterpret_cast<const float4*>(&Ws[(k4 * 4 + 1) * 128 + tc * 4]);
        const float4 w2 = *reinterpret_cast<const float4*>(&Ws[(k4 * 4 + 2) * 128 + tc * 4]);
        const float4 w3 = *reinterpret_cast<const float4*>(&Ws[(k4 * 4 + 3) * 128 + tc * 4]);
#pragma unroll
        for (int j = 0; j < 8; j++) {
            const float4 a = A4[arow[j] + k4];
            acc[j][0] = fmaf(a.x, w0.x, fmaf(a.y, w1.x, fmaf(a.z, w2.x, fmaf(a.w, w3.x, acc[j][0]))));
            acc[j][1] = fmaf(a.x, w0.y, fmaf(a.y, w1.y, fmaf(a.z, w2.y, fmaf(a.w, w3.y, acc[j][1]))));
            acc[j][2] = fmaf(a.x, w0.z, fmaf(a.y, w1.z, fmaf(a.z, w2.z, fmaf(a.w, w3.z, acc[j][2]))));
            acc[j][3] = fmaf(a.x, w0.w, fmaf(a.y, w1.w, fmaf(a.z, w2.w, fmaf(a.w, w3.w, acc[j][3]))));
        }
    }

#pragma unroll
    for (int j = 0; j < 8; j++) {
        const int r = r0 + j;
        if (r < nrows) {
            float4 o;
            o.x = acc[j][0]; o.y = acc[j][1]; o.z = acc[j][2]; o.w = acc[j][3];
            *reinterpret_cast<float4*>(&C[(size_t)r * 128 + tc * 4]) = o;
        }
    }
}

// ---------------- Gather (pull-style message passing) ----------------
// one wave per dst node; lane owns 2 consecutive cols; edge loop unrolled x4
// (4 independent scalar->vector load chains in flight)

__global__ __launch_bounds__(256) void k_gather(const float* __restrict__ hw,
                                                const float* __restrict__ dinv,
                                                const int* __restrict__ rowptr,
                                                const int* __restrict__ cnt,
                                                const int* __restrict__ esrc,
                                                const float* __restrict__ bias,
                                                float* __restrict__ outp, int n) {
    int wave = threadIdx.x >> 6;
    int lane = threadIdx.x & 63;
    int node = blockIdx.x * 4 + wave;
    if (node >= n) return;

    float di = dinv[node];
    int start = rowptr[node];
    int deg = cnt[node];

    const float2* hn = reinterpret_cast<const float2*>(hw + (size_t)node * 128);
    float2 v = hn[lane];
    float sw = di * di;                 // self-loop weight
    float acc0 = v.x * sw;
    float acc1 = v.y * sw;

    int j = 0;
    for (; j + 3 < deg; j += 4) {
        int s0 = esrc[start + j + 0];
        int s1 = esrc[start + j + 1];
        int s2 = esrc[start + j + 2];
        int s3 = esrc[start + j + 3];
        float w0 = dinv[s0] * di;
        float w1 = dinv[s1] * di;
        float w2 = dinv[s2] * di;
        float w3 = dinv[s3] * di;
        float2 u0 = reinterpret_cast<const float2*>(hw + (size_t)s0 * 128)[lane];
        float2 u1 = reinterpret_cast<const float2*>(hw + (size_t)s1 * 128)[lane];
        float2 u2 = reinterpret_cast<const float2*>(hw + (size_t)s2 * 128)[lane];
        float2 u3 = reinterpret_cast<const float2*>(hw + (size_t)s3 * 128)[lane];
        acc0 = fmaf(u0.x, w0, acc0); acc1 = fmaf(u0.y, w0, acc1);
        acc0 = fmaf(u1.x, w1, acc0); acc1 = fmaf(u1.y, w1, acc1);
        acc0 = fmaf(u2.x, w2, acc0); acc1 = fmaf(u2.y, w2, acc1);
        acc0 = fmaf(u3.x, w3, acc0); acc1 = fmaf(u3.y, w3, acc1);
    }
    for (; j < deg; j++) {
        int s = esrc[start + j];
        float w = dinv[s] * di;
        float2 u = reinterpret_cast<const float2*>(hw + (size_t)s * 128)[lane];
        acc0 = fmaf(u.x, w, acc0);
        acc1 = fmaf(u.y, w, acc1);
    }

    const float2* b2 = reinterpret_cast<const float2*>(bias);
    float2 bb = b2[lane];
    acc0 += bb.x;
    acc1 += bb.y;
    float2 o;
    o.x = acc0 > 0.0f ? acc0 : 0.0f;
    o.y = acc1 > 0.0f ? acc1 : 0.0f;
    reinterpret_cast<float2*>(outp + (size_t)node * 128)[lane] = o;
}

// ---------------- Max pool (post-ReLU, values >= 0) ----------------

__global__ __launch_bounds__(256) void k_pool(const float* __restrict__ h,
                                              int* __restrict__ pooledBits, int n) {
    int c = threadIdx.x & 127;
    int half = threadIdx.x >> 7;
    float m = 0.0f;
    for (int r = blockIdx.x * 2 + half; r < n; r += gridDim.x * 2)
        m = fmaxf(m, h[(size_t)r * 128 + c]);
    atomicMax(&pooledBits[c], __float_as_int(m));  // valid: m >= 0
}

__global__ __launch_bounds__(64) void k_fc(const int* __restrict__ pooledBits,
                                           const float* __restrict__ Wfc,
                                           const float* __restrict__ bfc,
                                           float* __restrict__ out) {
    int c = threadIdx.x;  // 0..63
    float acc = bfc[c];
    for (int k = 0; k < 128; k++)
        acc = fmaf(__int_as_float(pooledBits[k]), Wfc[k * 64 + c], acc);
    out[c] = acc;
}

// ---------------- launch ----------------

extern "C" void kernel_launch(void* const* d_in, const int* in_sizes, int n_in,
                              void* d_out, int out_size, void* d_ws, size_t ws_size,
                              hipStream_t stream) {
    const float* x   = (const float*)d_in[0];
    const int* edges = (const int*)d_in[1];
    const float* W1  = (const float*)d_in[2];
    const float* b1  = (const float*)d_in[3];
    const float* W2  = (const float*)d_in[4];
    const float* b2  = (const float*)d_in[5];
    const float* Wfc = (const float*)d_in[6];
    const float* bfc = (const float*)d_in[7];
    float* out = (float*)d_out;

    const int N = in_sizes[0] / 128;
    const int E = in_sizes[1] / 2;
    const int* esrc_in = edges;       // edge_index[0]
    const int* edst_in = edges + E;   // edge_index[1]

    // workspace layout (256B aligned chunks)
    auto align256 = [](size_t v) { return (v + 255) & ~(size_t)255; };
    char* p = (char*)d_ws;
    size_t off = 0;
    int* cnt      = (int*)(p + off); off = align256(off + (size_t)N * 4);
    int* rowptr   = (int*)(p + off); off = align256(off + (size_t)N * 4);
    int* cursor   = (int*)(p + off); off = align256(off + (size_t)N * 4);
    float* dinv   = (float*)(p + off); off = align256(off + (size_t)N * 4);
    int* bsum     = (int*)(p + off); off = align256(off + 256 * 4);
    int* pooled   = (int*)(p + off); off = align256(off + 128 * 4);
    int* esrc     = (int*)(p + off); off = align256(off + (size_t)E * 4);
    float* bufA   = (float*)(p + off); off = align256(off + (size_t)N * 128 * 4);
    float* bufB   = (float*)(p + off); off = align256(off + (size_t)N * 128 * 4);
    (void)ws_size; (void)n_in; (void)out_size;

    const int EB = (E + 255) / 256;       // 3125
    const int NB = (N + 255) / 256;       // 196 (<=256 for single-block scan)
    const int GB = (N + 63) / 64;         // gemm blocks (64 rows each)
    const int HB = (N + 3) / 4;           // gather blocks

    hipMemsetAsync(cnt, 0, (size_t)N * 4, stream);
    hipMemsetAsync(pooled, 0, 128 * 4, stream);

    k_count<<<EB, 256, 0, stream>>>(edst_in, cnt, E);
    k_dinv<<<NB, 256, 0, stream>>>(cnt, dinv, N);
    k_block_reduce<<<NB, 256, 0, stream>>>(cnt, bsum, N);
    k_scan_bsum<<<1, 256, 0, stream>>>(bsum, NB);
    k_scan_write<<<NB, 256, 0, stream>>>(cnt, bsum, rowptr, cursor, N);
    k_scatter<<<EB, 256, 0, stream>>>(esrc_in, edst_in, cursor, esrc, E);

    // layer 1
    k_gemm128<<<GB, 256, 0, stream>>>(x, W1, bufA, N);
    k_gather<<<HB, 256, 0, stream>>>(bufA, dinv, rowptr, cnt, esrc, b1, bufB, N);
    // layer 2
    k_gemm128<<<GB, 256, 0, stream>>>(bufB, W2, bufA, N);
    k_gather<<<HB, 256, 0, stream>>>(bufA, dinv, rowptr, cnt, esrc, b2, bufB, N);

    // pool + fc
    k_pool<<<512, 256, 0, stream>>>(bufB, pooled, N);
    k_fc<<<1, 64, 0, stream>>>(pooled, Wfc, bfc, out);
}

// Round 5
// 395.060 us; speedup vs baseline: 1.6280x; 1.0152x over previous
//
#include <hip/hip_runtime.h>
#include <cstdint>
#include <cstddef>

// ---------------- CSR build ----------------

__global__ __launch_bounds__(256) void k_count(const int* __restrict__ dst,
                                               int* __restrict__ cnt, int E) {
    int e = blockIdx.x * 256 + threadIdx.x;
    if (e < E) atomicAdd(&cnt[dst[e]], 1);
}

__global__ __launch_bounds__(256) void k_block_reduce(const int* __restrict__ cnt,
                                                      int* __restrict__ bsum, int n) {
    __shared__ int sd[256];
    int i = blockIdx.x * 256 + threadIdx.x;
    sd[threadIdx.x] = (i < n) ? cnt[i] : 0;
    __syncthreads();
    for (int s = 128; s > 0; s >>= 1) {
        if (threadIdx.x < s) sd[threadIdx.x] += sd[threadIdx.x + s];
        __syncthreads();
    }
    if (threadIdx.x == 0) bsum[blockIdx.x] = sd[0];
}

// single block, nb <= 256: in-place exclusive scan of bsum
__global__ __launch_bounds__(256) void k_scan_bsum(int* __restrict__ bsum, int nb) {
    __shared__ int sd[256];
    int t = threadIdx.x;
    int v = (t < nb) ? bsum[t] : 0;
    sd[t] = v;
    __syncthreads();
    for (int off = 1; off < 256; off <<= 1) {
        int add = (t >= off) ? sd[t - off] : 0;
        __syncthreads();
        sd[t] += add;
        __syncthreads();
    }
    if (t < nb) bsum[t] = sd[t] - v;  // exclusive
}

// scan within block + add block offset; also emits dinv = rsqrt(deg+1)
__global__ __launch_bounds__(256) void k_scan_write(const int* __restrict__ cnt,
                                                    const int* __restrict__ bsum,
                                                    int* __restrict__ rowptr,
                                                    int* __restrict__ cursor,
                                                    float* __restrict__ dinv, int n) {
    __shared__ int sd[256];
    int t = threadIdx.x;
    int i = blockIdx.x * 256 + t;
    int v = (i < n) ? cnt[i] : 0;
    sd[t] = v;
    __syncthreads();
    for (int off = 1; off < 256; off <<= 1) {
        int add = (t >= off) ? sd[t - off] : 0;
        __syncthreads();
        sd[t] += add;
        __syncthreads();
    }
    int excl = sd[t] - v + bsum[blockIdx.x];
    if (i < n) {
        rowptr[i] = excl;
        cursor[i] = excl;
        dinv[i] = rsqrtf((float)v + 1.0f);  // +1 self-loop, always > 0
    }
}

__global__ __launch_bounds__(256) void k_scatter(const int* __restrict__ src,
                                                 const int* __restrict__ dst,
                                                 int* __restrict__ cursor,
                                                 int* __restrict__ esrc, int E) {
    int e = blockIdx.x * 256 + threadIdx.x;
    if (e < E) {
        int d = dst[e];
        int pos = atomicAdd(&cursor[d], 1);
        esrc[pos] = src[e];
    }
}

// ---------------- GEMM: C[n x 128] = A[n x 128] @ W[128 x 128] ----------------
// 256 threads = 4 waves; tile 64 rows x 128 cols; K split into two 64-halves so
// the W LDS tile is 32 KB -> 4 blocks/CU (vs 2 at 64 KB). acc[8][4] = 32 chains.

__global__ __launch_bounds__(256, 4) void k_gemm128(const float* __restrict__ A,
                                                    const float* __restrict__ Wg,
                                                    float* __restrict__ C, int nrows) {
    __shared__ float Ws[64 * 128];  // 32 KB
    const int tid = threadIdx.x;
    const int tc = tid & 31;
    const int tr = tid >> 5;
    const int r0 = blockIdx.x * 64 + tr * 8;

    // clamp row indices so tail-block loads stay in bounds (stores are guarded)
    size_t arow[8];
#pragma unroll
    for (int j = 0; j < 8; j++) {
        int r = r0 + j;
        if (r > nrows - 1) r = nrows - 1;
        arow[j] = (size_t)r * 32;
    }

    float acc[8][4];
#pragma unroll
    for (int j = 0; j < 8; j++)
#pragma unroll
        for (int c = 0; c < 4; c++) acc[j][c] = 0.0f;

    const float4* A4 = reinterpret_cast<const float4*>(A);
    const float4* Wg4 = reinterpret_cast<const float4*>(Wg);
    float4* Ws4 = reinterpret_cast<float4*>(Ws);

    for (int half = 0; half < 2; half++) {
        // stage W rows [half*64, half*64+64) : 2048 float4, 8 per thread
#pragma unroll
        for (int i = 0; i < 8; i++) Ws4[tid + 256 * i] = Wg4[half * 2048 + tid + 256 * i];
        __syncthreads();

        for (int k4 = 0; k4 < 16; k4++) {
            const float4 w0 = *reinterpret_cast<const float4*>(&Ws[(k4 * 4 + 0) * 128 + tc * 4]);
            const float4 w1 = *reinterpret_cast<const float4*>(&Ws[(k4 * 4 + 1) * 128 + tc * 4]);
            const float4 w2 = *reinterpret_cast<const float4*>(&Ws[(k4 * 4 + 2) * 128 + tc * 4]);
            const float4 w3 = *reinterpret_cast<const float4*>(&Ws[(k4 * 4 + 3) * 128 + tc * 4]);
#pragma unroll
            for (int j = 0; j < 8; j++) {
                const float4 a = A4[arow[j] + half * 16 + k4];
                acc[j][0] = fmaf(a.x, w0.x, fmaf(a.y, w1.x, fmaf(a.z, w2.x, fmaf(a.w, w3.x, acc[j][0]))));
                acc[j][1] = fmaf(a.x, w0.y, fmaf(a.y, w1.y, fmaf(a.z, w2.y, fmaf(a.w, w3.y, acc[j][1]))));
                acc[j][2] = fmaf(a.x, w0.z, fmaf(a.y, w1.z, fmaf(a.z, w2.z, fmaf(a.w, w3.z, acc[j][2]))));
                acc[j][3] = fmaf(a.x, w0.w, fmaf(a.y, w1.w, fmaf(a.z, w2.w, fmaf(a.w, w3.w, acc[j][3]))));
            }
        }
        __syncthreads();
    }

#pragma unroll
    for (int j = 0; j < 8; j++) {
        const int r = r0 + j;
        if (r < nrows) {
            float4 o;
            o.x = acc[j][0]; o.y = acc[j][1]; o.z = acc[j][2]; o.w = acc[j][3];
            *reinterpret_cast<float4*>(&C[(size_t)r * 128 + tc * 4]) = o;
        }
    }
}

// ---------------- Gather (pull-style message passing) ----------------
// one wave per dst node; lane owns 2 consecutive cols; edge loop unrolled x8
// (8 independent 512 B row loads in flight per wave)

__global__ __launch_bounds__(256) void k_gather(const float* __restrict__ hw,
                                                const float* __restrict__ dinv,
                                                const int* __restrict__ rowptr,
                                                const int* __restrict__ cnt,
                                                const int* __restrict__ esrc,
                                                const float* __restrict__ bias,
                                                float* __restrict__ outp, int n) {
    int wave = threadIdx.x >> 6;
    int lane = threadIdx.x & 63;
    int node = blockIdx.x * 4 + wave;
    if (node >= n) return;

    float di = dinv[node];
    int start = rowptr[node];
    int deg = cnt[node];

    const float2* hn = reinterpret_cast<const float2*>(hw + (size_t)node * 128);
    float2 v = hn[lane];
    float sw = di * di;                 // self-loop weight
    float acc0 = v.x * sw;
    float acc1 = v.y * sw;

    int j = 0;
    for (; j + 7 < deg; j += 8) {
        int s[8]; float w[8]; float2 u[8];
#pragma unroll
        for (int t = 0; t < 8; t++) s[t] = esrc[start + j + t];
#pragma unroll
        for (int t = 0; t < 8; t++) u[t] = reinterpret_cast<const float2*>(hw + (size_t)s[t] * 128)[lane];
#pragma unroll
        for (int t = 0; t < 8; t++) w[t] = dinv[s[t]] * di;
#pragma unroll
        for (int t = 0; t < 8; t++) { acc0 = fmaf(u[t].x, w[t], acc0); acc1 = fmaf(u[t].y, w[t], acc1); }
    }
    for (; j < deg; j++) {
        int s = esrc[start + j];
        float w = dinv[s] * di;
        float2 u = reinterpret_cast<const float2*>(hw + (size_t)s * 128)[lane];
        acc0 = fmaf(u.x, w, acc0);
        acc1 = fmaf(u.y, w, acc1);
    }

    const float2* b2 = reinterpret_cast<const float2*>(bias);
    float2 bb = b2[lane];
    acc0 += bb.x;
    acc1 += bb.y;
    float2 o;
    o.x = acc0 > 0.0f ? acc0 : 0.0f;
    o.y = acc1 > 0.0f ? acc1 : 0.0f;
    reinterpret_cast<float2*>(outp + (size_t)node * 128)[lane] = o;
}

// ---------------- Gather #2 fused with max-pool ----------------
// same gather, but instead of writing h rows, reduce per-block column max in
// LDS and write one 128-float partial per block (values >= 0 post-ReLU).

__global__ __launch_bounds__(256) void k_gather_pool(const float* __restrict__ hw,
                                                     const float* __restrict__ dinv,
                                                     const int* __restrict__ rowptr,
                                                     const int* __restrict__ cnt,
                                                     const int* __restrict__ esrc,
                                                     const float* __restrict__ bias,
                                                     int* __restrict__ pooledPart, int n) {
    __shared__ int smax[128];
    int tid = threadIdx.x;
    int wave = tid >> 6;
    int lane = tid & 63;
    if (tid < 128) smax[tid] = 0;
    __syncthreads();

    int node = blockIdx.x * 4 + wave;
    if (node < n) {
        float di = dinv[node];
        int start = rowptr[node];
        int deg = cnt[node];

        const float2* hn = reinterpret_cast<const float2*>(hw + (size_t)node * 128);
        float2 v = hn[lane];
        float sw = di * di;
        float acc0 = v.x * sw;
        float acc1 = v.y * sw;

        int j = 0;
        for (; j + 7 < deg; j += 8) {
            int s[8]; float w[8]; float2 u[8];
#pragma unroll
            for (int t = 0; t < 8; t++) s[t] = esrc[start + j + t];
#pragma unroll
            for (int t = 0; t < 8; t++) u[t] = reinterpret_cast<const float2*>(hw + (size_t)s[t] * 128)[lane];
#pragma unroll
            for (int t = 0; t < 8; t++) w[t] = dinv[s[t]] * di;
#pragma unroll
            for (int t = 0; t < 8; t++) { acc0 = fmaf(u[t].x, w[t], acc0); acc1 = fmaf(u[t].y, w[t], acc1); }
        }
        for (; j < deg; j++) {
            int s = esrc[start + j];
            float w = dinv[s] * di;
            float2 u = reinterpret_cast<const float2*>(hw + (size_t)s * 128)[lane];
            acc0 = fmaf(u.x, w, acc0);
            acc1 = fmaf(u.y, w, acc1);
        }

        const float2* b2 = reinterpret_cast<const float2*>(bias);
        float2 bb = b2[lane];
        acc0 += bb.x;
        acc1 += bb.y;
        acc0 = acc0 > 0.0f ? acc0 : 0.0f;   // ReLU -> >= 0, int-compare trick valid
        acc1 = acc1 > 0.0f ? acc1 : 0.0f;
        atomicMax(&smax[lane * 2 + 0], __float_as_int(acc0));
        atomicMax(&smax[lane * 2 + 1], __float_as_int(acc1));
    }
    __syncthreads();
    if (tid < 128) pooledPart[(size_t)blockIdx.x * 128 + tid] = smax[tid];
}

// reduce partials: one block per column
__global__ __launch_bounds__(256) void k_pool2(const int* __restrict__ pooledPart,
                                               int* __restrict__ pooledBits, int nPart) {
    __shared__ int sd[256];
    int c = blockIdx.x;   // 0..127
    int t = threadIdx.x;
    int m = 0;
    for (int p = t; p < nPart; p += 256) {
        int v = pooledPart[(size_t)p * 128 + c];
        m = v > m ? v : m;   // post-ReLU bits: int compare == float compare
    }
    sd[t] = m;
    __syncthreads();
    for (int s = 128; s > 0; s >>= 1) {
        if (t < s) { int v = sd[t + s]; if (v > sd[t]) sd[t] = v; }
        __syncthreads();
    }
    if (t == 0) pooledBits[c] = sd[0];
}

__global__ __launch_bounds__(64) void k_fc(const int* __restrict__ pooledBits,
                                           const float* __restrict__ Wfc,
                                           const float* __restrict__ bfc,
                                           float* __restrict__ out) {
    int c = threadIdx.x;  // 0..63
    float acc = bfc[c];
    for (int k = 0; k < 128; k++)
        acc = fmaf(__int_as_float(pooledBits[k]), Wfc[k * 64 + c], acc);
    out[c] = acc;
}

// ---------------- launch ----------------

extern "C" void kernel_launch(void* const* d_in, const int* in_sizes, int n_in,
                              void* d_out, int out_size, void* d_ws, size_t ws_size,
                              hipStream_t stream) {
    const float* x   = (const float*)d_in[0];
    const int* edges = (const int*)d_in[1];
    const float* W1  = (const float*)d_in[2];
    const float* b1  = (const float*)d_in[3];
    const float* W2  = (const float*)d_in[4];
    const float* b2  = (const float*)d_in[5];
    const float* Wfc = (const float*)d_in[6];
    const float* bfc = (const float*)d_in[7];
    float* out = (float*)d_out;

    const int N = in_sizes[0] / 128;
    const int E = in_sizes[1] / 2;
    const int* esrc_in = edges;       // edge_index[0]
    const int* edst_in = edges + E;   // edge_index[1]

    // workspace layout (256B aligned chunks)
    auto align256 = [](size_t v) { return (v + 255) & ~(size_t)255; };
    char* p = (char*)d_ws;
    size_t off = 0;
    int* cnt      = (int*)(p + off); off = align256(off + (size_t)N * 4);
    int* rowptr   = (int*)(p + off); off = align256(off + (size_t)N * 4);
    int* cursor   = (int*)(p + off); off = align256(off + (size_t)N * 4);
    float* dinv   = (float*)(p + off); off = align256(off + (size_t)N * 4);
    int* bsum     = (int*)(p + off); off = align256(off + 256 * 4);
    int* pooled   = (int*)(p + off); off = align256(off + 128 * 4);
    int* esrc     = (int*)(p + off); off = align256(off + (size_t)E * 4);
    float* bufA   = (float*)(p + off); off = align256(off + (size_t)N * 128 * 4);
    float* bufB   = (float*)(p + off); off = align256(off + (size_t)N * 128 * 4);
    (void)ws_size; (void)n_in; (void)out_size;

    const int EB = (E + 255) / 256;       // edge blocks
    const int NB = (N + 255) / 256;       // node blocks (<=256 for single-block scan)
    const int GB = (N + 63) / 64;         // gemm blocks (64 rows each)
    const int HB = (N + 3) / 4;           // gather blocks (4 nodes each)

    int* pooledPart = (int*)bufB;         // reuse: 2nd gather no longer writes bufB

    hipMemsetAsync(cnt, 0, (size_t)N * 4, stream);

    k_count<<<EB, 256, 0, stream>>>(edst_in, cnt, E);
    k_block_reduce<<<NB, 256, 0, stream>>>(cnt, bsum, N);
    k_scan_bsum<<<1, 256, 0, stream>>>(bsum, NB);
    k_scan_write<<<NB, 256, 0, stream>>>(cnt, bsum, rowptr, cursor, dinv, N);
    k_scatter<<<EB, 256, 0, stream>>>(esrc_in, edst_in, cursor, esrc, E);

    // layer 1
    k_gemm128<<<GB, 256, 0, stream>>>(x, W1, bufA, N);
    k_gather<<<HB, 256, 0, stream>>>(bufA, dinv, rowptr, cnt, esrc, b1, bufB, N);
    // layer 2
    k_gemm128<<<GB, 256, 0, stream>>>(bufB, W2, bufA, N);
    k_gather_pool<<<HB, 256, 0, stream>>>(bufA, dinv, rowptr, cnt, esrc, b2, pooledPart, N);

    // pool reduce + fc
    k_pool2<<<128, 256, 0, stream>>>(pooledPart, pooled, HB);
    k_fc<<<1, 64, 0, stream>>>(pooled, Wfc, bfc, out);
}

// Round 6
// 379.982 us; speedup vs baseline: 1.6926x; 1.0397x over previous
//
#include <hip/hip_runtime.h>
#include <cstdint>
#include <cstddef>

// ---------------- CSR build ----------------

__global__ __launch_bounds__(256) void k_count(const int* __restrict__ dst,
                                               int* __restrict__ cnt, int E) {
    int e = blockIdx.x * 256 + threadIdx.x;
    if (e < E) atomicAdd(&cnt[dst[e]], 1);
}

__global__ __launch_bounds__(256) void k_block_reduce(const int* __restrict__ cnt,
                                                      int* __restrict__ bsum, int n) {
    __shared__ int sd[256];
    int i = blockIdx.x * 256 + threadIdx.x;
    sd[threadIdx.x] = (i < n) ? cnt[i] : 0;
    __syncthreads();
    for (int s = 128; s > 0; s >>= 1) {
        if (threadIdx.x < s) sd[threadIdx.x] += sd[threadIdx.x + s];
        __syncthreads();
    }
    if (threadIdx.x == 0) bsum[blockIdx.x] = sd[0];
}

// single block, nb <= 256: in-place exclusive scan of bsum
__global__ __launch_bounds__(256) void k_scan_bsum(int* __restrict__ bsum, int nb) {
    __shared__ int sd[256];
    int t = threadIdx.x;
    int v = (t < nb) ? bsum[t] : 0;
    sd[t] = v;
    __syncthreads();
    for (int off = 1; off < 256; off <<= 1) {
        int add = (t >= off) ? sd[t - off] : 0;
        __syncthreads();
        sd[t] += add;
        __syncthreads();
    }
    if (t < nb) bsum[t] = sd[t] - v;  // exclusive
}

// scan within block + add block offset; also emits dinv = rsqrt(deg+1)
__global__ __launch_bounds__(256) void k_scan_write(const int* __restrict__ cnt,
                                                    const int* __restrict__ bsum,
                                                    int* __restrict__ rowptr,
                                                    int* __restrict__ cursor,
                                                    float* __restrict__ dinv, int n) {
    __shared__ int sd[256];
    int t = threadIdx.x;
    int i = blockIdx.x * 256 + t;
    int v = (i < n) ? cnt[i] : 0;
    sd[t] = v;
    __syncthreads();
    for (int off = 1; off < 256; off <<= 1) {
        int add = (t >= off) ? sd[t - off] : 0;
        __syncthreads();
        sd[t] += add;
        __syncthreads();
    }
    int excl = sd[t] - v + bsum[blockIdx.x];
    if (i < n) {
        rowptr[i] = excl;
        cursor[i] = excl;
        dinv[i] = rsqrtf((float)v + 1.0f);  // +1 self-loop, always > 0
    }
}

__global__ __launch_bounds__(256) void k_scatter(const int* __restrict__ src,
                                                 const int* __restrict__ dst,
                                                 int* __restrict__ cursor,
                                                 int* __restrict__ esrc, int E) {
    int e = blockIdx.x * 256 + threadIdx.x;
    if (e < E) {
        int d = dst[e];
        int pos = atomicAdd(&cursor[d], 1);
        esrc[pos] = src[e];
    }
}

// ---------------- GEMM: C[n x 128] = A[n x 128] @ W[128 x 128] ----------------
// 256 threads = 4 waves; tile 64 rows x 128 cols. K in 4 chunks of 32.
// Per chunk: stage A-tile TRANSPOSED As[k][row] (coalesced float4 global reads)
// and W-chunk Ws[k][col]. Inner loop: thread (tr=tid>>4 -> 4 rows, tc=tid&15 ->
// 8 cols): 1 ds_read_b128 (A) + 2 ds_read_b128 (W) + 32 FMA per k.
// LDS = 32*68*4 + 32*128*4 = 25.1 KB -> 4 blocks/CU.

#define AP 68  // padded pitch for As rows (floats): banks spread, 16B aligned

__global__ __launch_bounds__(256, 4) void k_gemm128(const float* __restrict__ A,
                                                    const float* __restrict__ Wg,
                                                    float* __restrict__ C, int nrows) {
    __shared__ float As[32 * AP];    // [k][row], k<32, row<64
    __shared__ float Ws[32 * 128];   // [k][col]
    const int tid = threadIdx.x;
    const int tc = tid & 15;         // 8 cols: tc*8 .. tc*8+7
    const int tr = tid >> 4;         // 4 rows: tr*4 .. tr*4+3
    const int r0 = blockIdx.x * 64;

    float acc[4][8];
#pragma unroll
    for (int j = 0; j < 4; j++)
#pragma unroll
        for (int c = 0; c < 8; c++) acc[j][c] = 0.0f;

    const float4* A4 = reinterpret_cast<const float4*>(A);
    const float4* Wg4 = reinterpret_cast<const float4*>(Wg);
    float4* Ws4 = reinterpret_cast<float4*>(Ws);

    // staging indices: A side — 32 rows/pass, 8 float4 per row
    const int srow = tid >> 3;       // 0..31 (row within pass)
    const int sk4 = tid & 7;         // float4 index within 32-k chunk

    for (int kc = 0; kc < 4; kc++) {
        // stage W chunk: rows [kc*32, kc*32+32) of W, flat 1024 float4
#pragma unroll
        for (int i = 0; i < 4; i++) Ws4[tid + 256 * i] = Wg4[kc * 1024 + tid + 256 * i];
        // stage A chunk transposed: 2 passes of 32 rows
#pragma unroll
        for (int pass = 0; pass < 2; pass++) {
            int rl = srow + pass * 32;          // local row 0..63
            int rg = r0 + rl;                   // global row
            if (rg > nrows - 1) rg = nrows - 1; // clamp (stores guarded later)
            float4 av = A4[(size_t)rg * 32 + kc * 8 + sk4];
            int kb = sk4 * 4;                   // k within chunk
            As[(kb + 0) * AP + rl] = av.x;
            As[(kb + 1) * AP + rl] = av.y;
            As[(kb + 2) * AP + rl] = av.z;
            As[(kb + 3) * AP + rl] = av.w;
        }
        __syncthreads();

#pragma unroll 4
        for (int k = 0; k < 32; k++) {
            const float4 a = *reinterpret_cast<const float4*>(&As[k * AP + tr * 4]);
            const float4 w0 = *reinterpret_cast<const float4*>(&Ws[k * 128 + tc * 8]);
            const float4 w1 = *reinterpret_cast<const float4*>(&Ws[k * 128 + tc * 8 + 4]);
            const float av4[4] = {a.x, a.y, a.z, a.w};
            const float wv[8] = {w0.x, w0.y, w0.z, w0.w, w1.x, w1.y, w1.z, w1.w};
#pragma unroll
            for (int j = 0; j < 4; j++)
#pragma unroll
                for (int c = 0; c < 8; c++)
                    acc[j][c] = fmaf(av4[j], wv[c], acc[j][c]);
        }
        __syncthreads();
    }

#pragma unroll
    for (int j = 0; j < 4; j++) {
        const int r = r0 + tr * 4 + j;
        if (r < nrows) {
            float4 o0, o1;
            o0.x = acc[j][0]; o0.y = acc[j][1]; o0.z = acc[j][2]; o0.w = acc[j][3];
            o1.x = acc[j][4]; o1.y = acc[j][5]; o1.z = acc[j][6]; o1.w = acc[j][7];
            float* cp = &C[(size_t)r * 128 + tc * 8];
            *reinterpret_cast<float4*>(cp) = o0;
            *reinterpret_cast<float4*>(cp + 4) = o1;
        }
    }
}

// ---------------- Gather (pull-style message passing) ----------------
// one wave per dst node; lane owns 2 consecutive cols; edge loop unrolled x8

__global__ __launch_bounds__(256) void k_gather(const float* __restrict__ hw,
                                                const float* __restrict__ dinv,
                                                const int* __restrict__ rowptr,
                                                const int* __restrict__ cnt,
                                                const int* __restrict__ esrc,
                                                const float* __restrict__ bias,
                                                float* __restrict__ outp, int n) {
    int wave = threadIdx.x >> 6;
    int lane = threadIdx.x & 63;
    int node = blockIdx.x * 4 + wave;
    if (node >= n) return;

    float di = dinv[node];
    int start = rowptr[node];
    int deg = cnt[node];

    const float2* hn = reinterpret_cast<const float2*>(hw + (size_t)node * 128);
    float2 v = hn[lane];
    float sw = di * di;                 // self-loop weight
    float acc0 = v.x * sw;
    float acc1 = v.y * sw;

    int j = 0;
    for (; j + 7 < deg; j += 8) {
        int s[8]; float w[8]; float2 u[8];
#pragma unroll
        for (int t = 0; t < 8; t++) s[t] = esrc[start + j + t];
#pragma unroll
        for (int t = 0; t < 8; t++) u[t] = reinterpret_cast<const float2*>(hw + (size_t)s[t] * 128)[lane];
#pragma unroll
        for (int t = 0; t < 8; t++) w[t] = dinv[s[t]] * di;
#pragma unroll
        for (int t = 0; t < 8; t++) { acc0 = fmaf(u[t].x, w[t], acc0); acc1 = fmaf(u[t].y, w[t], acc1); }
    }
    for (; j < deg; j++) {
        int s = esrc[start + j];
        float w = dinv[s] * di;
        float2 u = reinterpret_cast<const float2*>(hw + (size_t)s * 128)[lane];
        acc0 = fmaf(u.x, w, acc0);
        acc1 = fmaf(u.y, w, acc1);
    }

    const float2* b2 = reinterpret_cast<const float2*>(bias);
    float2 bb = b2[lane];
    acc0 += bb.x;
    acc1 += bb.y;
    float2 o;
    o.x = acc0 > 0.0f ? acc0 : 0.0f;
    o.y = acc1 > 0.0f ? acc1 : 0.0f;
    reinterpret_cast<float2*>(outp + (size_t)node * 128)[lane] = o;
}

// ---------------- Gather #2 fused with max-pool ----------------

__global__ __launch_bounds__(256) void k_gather_pool(const float* __restrict__ hw,
                                                     const float* __restrict__ dinv,
                                                     const int* __restrict__ rowptr,
                                                     const int* __restrict__ cnt,
                                                     const int* __restrict__ esrc,
                                                     const float* __restrict__ bias,
                                                     int* __restrict__ pooledPart, int n) {
    __shared__ int smax[128];
    int tid = threadIdx.x;
    int wave = tid >> 6;
    int lane = tid & 63;
    if (tid < 128) smax[tid] = 0;
    __syncthreads();

    int node = blockIdx.x * 4 + wave;
    if (node < n) {
        float di = dinv[node];
        int start = rowptr[node];
        int deg = cnt[node];

        const float2* hn = reinterpret_cast<const float2*>(hw + (size_t)node * 128);
        float2 v = hn[lane];
        float sw = di * di;
        float acc0 = v.x * sw;
        float acc1 = v.y * sw;

        int j = 0;
        for (; j + 7 < deg; j += 8) {
            int s[8]; float w[8]; float2 u[8];
#pragma unroll
            for (int t = 0; t < 8; t++) s[t] = esrc[start + j + t];
#pragma unroll
            for (int t = 0; t < 8; t++) u[t] = reinterpret_cast<const float2*>(hw + (size_t)s[t] * 128)[lane];
#pragma unroll
            for (int t = 0; t < 8; t++) w[t] = dinv[s[t]] * di;
#pragma unroll
            for (int t = 0; t < 8; t++) { acc0 = fmaf(u[t].x, w[t], acc0); acc1 = fmaf(u[t].y, w[t], acc1); }
        }
        for (; j < deg; j++) {
            int s = esrc[start + j];
            float w = dinv[s] * di;
            float2 u = reinterpret_cast<const float2*>(hw + (size_t)s * 128)[lane];
            acc0 = fmaf(u.x, w, acc0);
            acc1 = fmaf(u.y, w, acc1);
        }

        const float2* b2 = reinterpret_cast<const float2*>(bias);
        float2 bb = b2[lane];
        acc0 += bb.x;
        acc1 += bb.y;
        acc0 = acc0 > 0.0f ? acc0 : 0.0f;   // ReLU -> >= 0, int-compare trick valid
        acc1 = acc1 > 0.0f ? acc1 : 0.0f;
        atomicMax(&smax[lane * 2 + 0], __float_as_int(acc0));
        atomicMax(&smax[lane * 2 + 1], __float_as_int(acc1));
    }
    __syncthreads();
    if (tid < 128) pooledPart[(size_t)blockIdx.x * 128 + tid] = smax[tid];
}

// reduce partials: coalesced — each block scans contiguous rows (2 rows/iter),
// LDS col-max, then 128 global atomicMax per block (values >= 0).

__global__ __launch_bounds__(256) void k_pool2(const int* __restrict__ pooledPart,
                                               int* __restrict__ pooledBits, int nPart) {
    __shared__ int smax[128];
    int tid = threadIdx.x;
    int c = tid & 127;
    int rh = tid >> 7;   // 0/1
    if (tid < 128) smax[tid] = 0;
    __syncthreads();
    int m = 0;
    for (int p = blockIdx.x * 2 + rh; p < nPart; p += gridDim.x * 2) {
        int v = pooledPart[(size_t)p * 128 + c];
        m = v > m ? v : m;   // post-ReLU bits: int compare == float compare
    }
    atomicMax(&smax[c], m);
    __syncthreads();
    if (tid < 128) atomicMax(&pooledBits[tid], smax[tid]);
}

__global__ __launch_bounds__(64) void k_fc(const int* __restrict__ pooledBits,
                                           const float* __restrict__ Wfc,
                                           const float* __restrict__ bfc,
                                           float* __restrict__ out) {
    int c = threadIdx.x;  // 0..63
    float acc = bfc[c];
    for (int k = 0; k < 128; k++)
        acc = fmaf(__int_as_float(pooledBits[k]), Wfc[k * 64 + c], acc);
    out[c] = acc;
}

// ---------------- launch ----------------

extern "C" void kernel_launch(void* const* d_in, const int* in_sizes, int n_in,
                              void* d_out, int out_size, void* d_ws, size_t ws_size,
                              hipStream_t stream) {
    const float* x   = (const float*)d_in[0];
    const int* edges = (const int*)d_in[1];
    const float* W1  = (const float*)d_in[2];
    const float* b1  = (const float*)d_in[3];
    const float* W2  = (const float*)d_in[4];
    const float* b2  = (const float*)d_in[5];
    const float* Wfc = (const float*)d_in[6];
    const float* bfc = (const float*)d_in[7];
    float* out = (float*)d_out;

    const int N = in_sizes[0] / 128;
    const int E = in_sizes[1] / 2;
    const int* esrc_in = edges;       // edge_index[0]
    const int* edst_in = edges + E;   // edge_index[1]

    // workspace layout (256B aligned chunks)
    auto align256 = [](size_t v) { return (v + 255) & ~(size_t)255; };
    char* p = (char*)d_ws;
    size_t off = 0;
    int* cnt      = (int*)(p + off); off = align256(off + (size_t)N * 4);
    int* rowptr   = (int*)(p + off); off = align256(off + (size_t)N * 4);
    int* cursor   = (int*)(p + off); off = align256(off + (size_t)N * 4);
    float* dinv   = (float*)(p + off); off = align256(off + (size_t)N * 4);
    int* bsum     = (int*)(p + off); off = align256(off + 256 * 4);
    int* pooled   = (int*)(p + off); off = align256(off + 128 * 4);
    int* esrc     = (int*)(p + off); off = align256(off + (size_t)E * 4);
    float* bufA   = (float*)(p + off); off = align256(off + (size_t)N * 128 * 4);
    float* bufB   = (float*)(p + off); off = align256(off + (size_t)N * 128 * 4);
    (void)ws_size; (void)n_in; (void)out_size;

    const int EB = (E + 255) / 256;       // edge blocks
    const int NB = (N + 255) / 256;       // node blocks (<=256 for single-block scan)
    const int GB = (N + 63) / 64;         // gemm blocks (64 rows each)
    const int HB = (N + 3) / 4;           // gather blocks (4 nodes each)

    int* pooledPart = (int*)bufB;         // reuse: 2nd gather no longer writes bufB

    hipMemsetAsync(cnt, 0, (size_t)N * 4, stream);
    hipMemsetAsync(pooled, 0, 128 * 4, stream);

    k_count<<<EB, 256, 0, stream>>>(edst_in, cnt, E);
    k_block_reduce<<<NB, 256, 0, stream>>>(cnt, bsum, N);
    k_scan_bsum<<<1, 256, 0, stream>>>(bsum, NB);
    k_scan_write<<<NB, 256, 0, stream>>>(cnt, bsum, rowptr, cursor, dinv, N);
    k_scatter<<<EB, 256, 0, stream>>>(esrc_in, edst_in, cursor, esrc, E);

    // layer 1
    k_gemm128<<<GB, 256, 0, stream>>>(x, W1, bufA, N);
    k_gather<<<HB, 256, 0, stream>>>(bufA, dinv, rowptr, cnt, esrc, b1, bufB, N);
    // layer 2
    k_gemm128<<<GB, 256, 0, stream>>>(bufB, W2, bufA, N);
    k_gather_pool<<<HB, 256, 0, stream>>>(bufA, dinv, rowptr, cnt, esrc, b2, pooledPart, N);

    // pool reduce + fc
    k_pool2<<<128, 256, 0, stream>>>(pooledPart, pooled, HB);
    k_fc<<<1, 64, 0, stream>>>(pooled, Wfc, bfc, out);
}